// Round 1
// baseline (9504.295 us; speedup 1.0000x reference)
//
#include <hip/hip_runtime.h>
#include <hip/hip_bf16.h>

// Problem constants
#define NB 8       // batch
#define NH 16      // heads
#define NBH 128    // NB*NH
#define LS 1024    // sequence length
#define DD 64      // head dim
#define DM 1024    // d_model = NH*DD
#define QT 16      // q rows per attn block
#define KT 128     // k rows staged per chunk
#define NCH 8      // LS/KT chunks
#define SCALEF 0.125f  // 1/sqrt(64)

// ---------------------------------------------------------------------------
// Gate kernel: gate[b,h,k] = sigmoid(W2 . tanh(W1 @ pt[b,h,k] + b1) + b2)
// One wave per row; block = 256 threads = 4 rows.  (unchanged)
// ---------------------------------------------------------------------------
__global__ __launch_bounds__(256) void gate_kernel(
    const float* __restrict__ pt, const float* __restrict__ W1,
    const float* __restrict__ b1, const float* __restrict__ W2,
    const float* __restrict__ b2, float* __restrict__ gate)
{
    int row  = blockIdx.x * 4 + (threadIdx.x >> 6);   // < NBH*LS
    int lane = threadIdx.x & 63;
    const float* x = pt + (size_t)row * DD;
    float xv = x[lane];                                // lane d holds x[d]
    float acc = b1[lane];
    const float* w1r = W1 + lane * DD;                 // W1[e][d], row e
    #pragma unroll 16
    for (int d = 0; d < DD; ++d)
        acc += w1r[d] * __shfl(xv, d);
    float h = tanhf(acc);
    float r = W2[lane] * h;
    #pragma unroll
    for (int off = 32; off > 0; off >>= 1)
        r += __shfl_down(r, off);
    if (lane == 0)
        gate[row] = 1.0f / (1.0f + expf(-(r + b2[0])));
}

// ---------------------------------------------------------------------------
// Fused attention, register-resident scores.
// Block: 256 threads (4 waves), one (bh, 16-q-row tile).
// Thread layout (phases A/B): qg=(l>>3)*2 -> 2 q rows; k = w*32+(l&7)*4 per
//   chunk -> scores sc[8][2][4] = 64 VGPRs/thread, never touching LDS.
// LDS: sKV 128x68 f32 (34.0KB, col-swizzled) + sQ 16x68 (4.25KB)
//      + sW 16x132 (8.25KB) + red 256B  = 46.8KB -> 3 blocks/CU (12 waves),
//      vs previous 136.5KB -> 1 block/CU (4 waves). That occupancy jump is
//      the point of this revision.
// ---------------------------------------------------------------------------
__global__ __launch_bounds__(256, 3) void attn_kernel(
    const float* __restrict__ Q, const float* __restrict__ Kmat,
    const float* __restrict__ V, const float* __restrict__ bias,
    const float* __restrict__ gate, float* __restrict__ Wout,
    __hip_bfloat16* __restrict__ tmp)
{
    __shared__ __align__(16) float sKV[KT][DD + 4];   // K/V staging (swizzled)
    __shared__ __align__(16) float sQ[QT][DD + 4];    // q tile (pre-scaled)
    __shared__ __align__(16) float sW[QT][KT + 4];    // per-chunk weights for PV
    __shared__ float red[4][QT];                      // cross-wave softmax reduce

    const int bh = blockIdx.y;
    const int q0 = blockIdx.x * QT;
    const int t  = threadIdx.x;
    const int w  = t >> 6;           // wave id 0..3
    const int l  = t & 63;           // lane
    const size_t hoff = (size_t)bh * LS * DD;

    const int qg   = (l >> 3) * 2;       // this thread's 2 q rows
    const int kbw  = w * 32;             // wave's k strip base within chunk
    const int krow = kbw + (l & 7) * 4;  // thread's 4 k rows within chunk
    const int sxz  = (l & 7) & 3;        // == ((krow>>2)&3), swizzle key

    // ---- stage Q tile (scaled); one float4 per thread ----
    {
        const float4* g = (const float4*)(Q + hoff + (size_t)q0 * DD);
        int r = t >> 4, c = t & 15;
        float4 v4 = g[r * 16 + c];
        v4.x *= SCALEF; v4.y *= SCALEF; v4.z *= SCALEF; v4.w *= SCALEF;
        ((float4*)sQ)[r * 17 + c] = v4;
    }
    __syncthreads();

    float sc[NCH][2][4];   // register-resident scores -> weights

    // ---- Phase A: scores = scale*QK^T + bias (registers) ----
    #pragma unroll
    for (int ch = 0; ch < NCH; ++ch) {
        __syncthreads();   // protect sKV reuse from previous chunk
        {
            // stage K chunk, column-swizzled: c' = c ^ ((r>>2)&3)
            const float4* g = (const float4*)(Kmat + hoff + (size_t)(ch * KT) * DD);
            #pragma unroll
            for (int it = 0; it < 8; ++it) {
                int idx = t + it * 256;
                int r = idx >> 4, c = idx & 15;
                ((float4*)sKV)[r * 17 + (c ^ ((r >> 2) & 3))] = g[r * 16 + c];
            }
        }
        __syncthreads();
        float acc[2][4];
        #pragma unroll
        for (int j = 0; j < 2; ++j)
            #pragma unroll
            for (int i = 0; i < 4; ++i) acc[j][i] = 0.0f;
        #pragma unroll
        for (int dv = 0; dv < 16; ++dv) {
            float4 kf[4];
            #pragma unroll
            for (int i = 0; i < 4; ++i)   // 8 distinct addrs, 8-way broadcast, 2-way banks
                kf[i] = ((const float4*)sKV)[(krow + i) * 17 + (dv ^ sxz)];
            #pragma unroll
            for (int j = 0; j < 2; ++j) {
                float4 qf = ((const float4*)sQ)[(qg + j) * 17 + dv]; // 8-lane broadcast
                #pragma unroll
                for (int i = 0; i < 4; ++i)
                    acc[j][i] += qf.x * kf[i].x + qf.y * kf[i].y +
                                 qf.z * kf[i].z + qf.w * kf[i].w;
            }
        }
        #pragma unroll
        for (int j = 0; j < 2; ++j) {
            float4 b4 = *(const float4*)(bias +
                ((size_t)bh * LS + q0 + qg + j) * LS + ch * KT + krow);
            sc[ch][j][0] = acc[j][0] + b4.x;
            sc[ch][j][1] = acc[j][1] + b4.y;
            sc[ch][j][2] = acc[j][2] + b4.z;
            sc[ch][j][3] = acc[j][3] + b4.w;
        }
    }

    // ---- Phase B: softmax in registers ----
    float m[2] = {-1e30f, -1e30f};
    #pragma unroll
    for (int ch = 0; ch < NCH; ++ch)
        #pragma unroll
        for (int j = 0; j < 2; ++j)
            #pragma unroll
            for (int i = 0; i < 4; ++i)
                m[j] = fmaxf(m[j], sc[ch][j][i]);
    #pragma unroll
    for (int off = 1; off <= 4; off <<= 1) {   // reduce over k-lanes (bits 0..2)
        m[0] = fmaxf(m[0], __shfl_xor(m[0], off));
        m[1] = fmaxf(m[1], __shfl_xor(m[1], off));
    }
    if ((l & 7) == 0) { red[w][qg] = m[0]; red[w][qg + 1] = m[1]; }
    __syncthreads();
    #pragma unroll
    for (int j = 0; j < 2; ++j)
        m[j] = fmaxf(fmaxf(red[0][qg + j], red[1][qg + j]),
                     fmaxf(red[2][qg + j], red[3][qg + j]));
    float zs[2] = {0.0f, 0.0f};
    #pragma unroll
    for (int ch = 0; ch < NCH; ++ch)
        #pragma unroll
        for (int j = 0; j < 2; ++j)
            #pragma unroll
            for (int i = 0; i < 4; ++i) {
                float e = __expf(sc[ch][j][i] - m[j]);
                sc[ch][j][i] = e;
                zs[j] += e;
            }
    #pragma unroll
    for (int off = 1; off <= 4; off <<= 1) {
        zs[0] += __shfl_xor(zs[0], off);
        zs[1] += __shfl_xor(zs[1], off);
    }
    __syncthreads();   // all reads of red (max) done before overwrite
    if ((l & 7) == 0) { red[w][qg] = zs[0]; red[w][qg + 1] = zs[1]; }
    __syncthreads();
    float inv[2];
    #pragma unroll
    for (int j = 0; j < 2; ++j)
        inv[j] = 1.0f / (red[0][qg + j] + red[1][qg + j] +
                         red[2][qg + j] + red[3][qg + j]);

    // ---- gate multiply; write weights straight from registers ----
    const float* grow = gate + (size_t)bh * LS;
    #pragma unroll
    for (int ch = 0; ch < NCH; ++ch) {
        const int kg = ch * KT + krow;
        float4 g4 = *(const float4*)(grow + kg);
        #pragma unroll
        for (int j = 0; j < 2; ++j) {
            float4 w4;
            w4.x = sc[ch][j][0] * inv[j] * g4.x;
            w4.y = sc[ch][j][1] * inv[j] * g4.y;
            w4.z = sc[ch][j][2] * inv[j] * g4.z;
            w4.w = sc[ch][j][3] * inv[j] * g4.w;
            sc[ch][j][0] = w4.x; sc[ch][j][1] = w4.y;
            sc[ch][j][2] = w4.z; sc[ch][j][3] = w4.w;
            *(float4*)(Wout + ((size_t)bh * LS + q0 + qg + j) * LS + kg) = w4;
        }
    }

    // ---- Phase C: O = W @ V; wave w owns k strip [kbw, kbw+32) per chunk ----
    const int dc = l & 15;          // float4 column of d
    const int rg = (l >> 4) * 4;    // 4 q rows for PV
    float4 oacc[4];
    #pragma unroll
    for (int j = 0; j < 4; ++j) oacc[j] = make_float4(0.f, 0.f, 0.f, 0.f);
    #pragma unroll
    for (int ch = 0; ch < NCH; ++ch) {
        __syncthreads();   // protect sW & sKV from previous chunk reads
        // spill this chunk's weights from regs into sW (the k->d transpose)
        #pragma unroll
        for (int j = 0; j < 2; ++j)
            *(float4*)&sW[qg + j][krow] = make_float4(
                sc[ch][j][0], sc[ch][j][1], sc[ch][j][2], sc[ch][j][3]);
        {
            // stage V chunk, same swizzle as K
            const float4* g = (const float4*)(V + hoff + (size_t)(ch * KT) * DD);
            #pragma unroll
            for (int it = 0; it < 8; ++it) {
                int idx = t + it * 256;
                int r = idx >> 4, c = idx & 15;
                ((float4*)sKV)[r * 17 + (c ^ ((r >> 2) & 3))] = g[r * 16 + c];
            }
        }
        __syncthreads();
        #pragma unroll
        for (int kk = 0; kk < 32; kk += 4) {
            const int kr  = kbw + kk;
            const int sz2 = (kk >> 2) & 3;   // == ((kr>>2)&3) since kbw%32==0
            float4 vf[4];
            #pragma unroll
            for (int i = 0; i < 4; ++i)
                vf[i] = ((const float4*)sKV)[(kr + i) * 17 + (dc ^ sz2)];
            #pragma unroll
            for (int j = 0; j < 4; ++j) {
                float4 wf = *(const float4*)&sW[rg + j][kr];  // 16-lane broadcast
                oacc[j].x += wf.x * vf[0].x + wf.y * vf[1].x + wf.z * vf[2].x + wf.w * vf[3].x;
                oacc[j].y += wf.x * vf[0].y + wf.y * vf[1].y + wf.z * vf[2].y + wf.w * vf[3].y;
                oacc[j].z += wf.x * vf[0].z + wf.y * vf[1].z + wf.z * vf[2].z + wf.w * vf[3].z;
                oacc[j].w += wf.x * vf[0].w + wf.y * vf[1].w + wf.z * vf[2].w + wf.w * vf[3].w;
            }
        }
    }
    __syncthreads();
    // cross-wave reduce of O partials through sKV (16KB region)
    {
        float4* redO = (float4*)sKV;   // [4 waves][16 rows][16 f4]
        #pragma unroll
        for (int j = 0; j < 4; ++j)
            redO[(w * 16 + rg + j) * 16 + dc] = oacc[j];
    }
    __syncthreads();
    {
        const int r = t >> 4, c = t & 15;
        float4 a0 = ((const float4*)sKV)[(0 * 16 + r) * 16 + c];
        float4 a1 = ((const float4*)sKV)[(1 * 16 + r) * 16 + c];
        float4 a2 = ((const float4*)sKV)[(2 * 16 + r) * 16 + c];
        float4 a3 = ((const float4*)sKV)[(3 * 16 + r) * 16 + c];
        float sx = a0.x + a1.x + a2.x + a3.x;
        float sy = a0.y + a1.y + a2.y + a3.y;
        float sz = a0.z + a1.z + a2.z + a3.z;
        float sw = a0.w + a1.w + a2.w + a3.w;
        const int b = bh >> 4, h = bh & 15;
        __hip_bfloat16* xp = tmp + ((size_t)(b * LS + q0 + r)) * DM + h * DD + c * 4;
        xp[0] = __float2bfloat16(sx);
        xp[1] = __float2bfloat16(sy);
        xp[2] = __float2bfloat16(sz);
        xp[3] = __float2bfloat16(sw);
    }
}

// ---------------------------------------------------------------------------
// Output projection: out[m][n] = b_out[n] + sum_k X[m][k] * W_out[n][k]
// X: bf16 [8192][1024] in ws; tile 128x128, K-step 64, 8x8 micro-tile.
// (unchanged this round)
// ---------------------------------------------------------------------------
#define PM 128
#define PN 128
__global__ __launch_bounds__(256) void proj_kernel(
    const __hip_bfloat16* __restrict__ X, const float* __restrict__ Wt,
    const float* __restrict__ bo, float* __restrict__ out)
{
    __shared__ __align__(16) float sX[PM][DD + 4];
    __shared__ __align__(16) float sW[PN][DD + 4];
    const int m0 = blockIdx.y * PM;
    const int n0 = blockIdx.x * PN;
    const int t  = threadIdx.x;
    const int mg = (t >> 4) * 8;
    const int ng = (t & 15) * 8;
    float acc[8][8];
    #pragma unroll
    for (int j = 0; j < 8; ++j)
        #pragma unroll
        for (int i = 0; i < 8; ++i) acc[j][i] = 0.0f;

    for (int kb = 0; kb < DM; kb += 64) {
        __syncthreads();
        for (int i = t; i < PM * 8; i += 256) {
            int r = i >> 3, c = i & 7;
            union { float4 f; unsigned short u[8]; } uu;
            uu.f = *(const float4*)(X + (size_t)(m0 + r) * DM + kb + c * 8);
            float xs[8];
            #pragma unroll
            for (int z = 0; z < 8; ++z)
                xs[z] = __uint_as_float(((unsigned)uu.u[z]) << 16);
            float4 lo = {xs[0], xs[1], xs[2], xs[3]};
            float4 hi = {xs[4], xs[5], xs[6], xs[7]};
            ((float4*)sX)[r * 17 + c * 2]     = lo;
            ((float4*)sX)[r * 17 + c * 2 + 1] = hi;
        }
        for (int i = t; i < PN * 16; i += 256) {
            int r = i >> 4, c = i & 15;
            ((float4*)sW)[r * 17 + c] =
                *(const float4*)(Wt + (size_t)(n0 + r) * DM + kb + c * 4);
        }
        __syncthreads();
        #pragma unroll 4
        for (int dv = 0; dv < 16; ++dv) {
            float4 xf[8], wf[8];
            #pragma unroll
            for (int j = 0; j < 8; ++j)
                xf[j] = ((const float4*)sX)[(mg + j) * 17 + dv];
            #pragma unroll
            for (int i = 0; i < 8; ++i)
                wf[i] = ((const float4*)sW)[(ng + i) * 17 + dv];
            #pragma unroll
            for (int j = 0; j < 8; ++j)
                #pragma unroll
                for (int i = 0; i < 8; ++i)
                    acc[j][i] += xf[j].x * wf[i].x + xf[j].y * wf[i].y +
                                 xf[j].z * wf[i].z + xf[j].w * wf[i].w;
        }
    }
    #pragma unroll
    for (int j = 0; j < 8; ++j) {
        float* orow = out + (size_t)(m0 + mg + j) * DM + n0 + ng;
        float4 r0, r1;
        r0.x = acc[j][0] + bo[n0 + ng + 0];
        r0.y = acc[j][1] + bo[n0 + ng + 1];
        r0.z = acc[j][2] + bo[n0 + ng + 2];
        r0.w = acc[j][3] + bo[n0 + ng + 3];
        r1.x = acc[j][4] + bo[n0 + ng + 4];
        r1.y = acc[j][5] + bo[n0 + ng + 5];
        r1.z = acc[j][6] + bo[n0 + ng + 6];
        r1.w = acc[j][7] + bo[n0 + ng + 7];
        *(float4*)orow       = r0;
        *(float4*)(orow + 4) = r1;
    }
}

// ---------------------------------------------------------------------------
extern "C" void kernel_launch(void* const* d_in, const int* in_sizes, int n_in,
                              void* d_out, int out_size, void* d_ws, size_t ws_size,
                              hipStream_t stream) {
    const float* q    = (const float*)d_in[0];
    const float* k    = (const float*)d_in[1];
    const float* v    = (const float*)d_in[2];
    const float* pt   = (const float*)d_in[3];
    const float* bias = (const float*)d_in[4];
    const float* W1   = (const float*)d_in[5];
    const float* b1   = (const float*)d_in[6];
    const float* W2   = (const float*)d_in[7];
    const float* b2   = (const float*)d_in[8];
    const float* Wo   = (const float*)d_in[9];
    const float* bo   = (const float*)d_in[10];

    float* out_graph   = (float*)d_out;                        // [8,1024,1024]
    float* out_weights = (float*)d_out + (size_t)NB * LS * DM; // [8,16,1024,1024]

    // ws layout: gate f32 [NBH*LS] (512KB) | tmp bf16 [NB*LS*DM] (16MB)
    float* gate = (float*)d_ws;
    __hip_bfloat16* tmp = (__hip_bfloat16*)((char*)d_ws + (size_t)NBH * LS * 4);

    gate_kernel<<<dim3(NBH * LS / 4), dim3(256), 0, stream>>>(
        pt, W1, b1, W2, b2, gate);
    attn_kernel<<<dim3(LS / QT, NBH), dim3(256), 0, stream>>>(
        q, k, v, bias, gate, out_weights, tmp);
    proj_kernel<<<dim3(DM / PN, NB * LS / PM), dim3(256), 0, stream>>>(
        tmp, Wo, bo, out_graph);
}